// Round 7
// baseline (736.724 us; speedup 1.0000x reference)
//
#include <hip/hip_runtime.h>
#include <hip/hip_bf16.h>
#include <hip/hip_cooperative_groups.h>

namespace cg = cooperative_groups;

// ---------------------------------------------------------------------------
// GraphSAGE 3-layer encoder, fp32 in/out.
//   per layer: h_out = relu?( mean_agg(h)@Wl + b + h@Wr )
// Identity: segment_sum(h[src])@Wl == segment_sum((h@Wl)[src])
//   -> project first (MFMA bf16), aggregate small vectors via CSR gather.
// R13 -> R14:
//   * R13 post-mortem: proj2/3 LDS port ~neutral (-2.5 us) -> the ~283 us
//     "rest" is NOT proj-side. Bottom-up budget (traffic/BW) explains only
//     ~200 us of 333; residual ~ 2x59us harness fills + launch gaps across
//     12 serial dispatches. Most compressible controllable item: the
//     6-launch CSR chain (tiny serial kernels, incl. 1-block scan_top).
//   * R14: ONE cooperative kernel builds the whole CSR (zero -> hist ->
//     reduce -> scan(partials) -> scan_final -> fill) with grid.sync()
//     between phases. Grid 782x256 all-resident (4 waves/blk, low VGPR).
//     Removes 5 launches + tails. Everything else untouched.
// ---------------------------------------------------------------------------

typedef __attribute__((ext_vector_type(8))) short short8;
typedef __attribute__((ext_vector_type(4))) float f32x4;

__device__ inline unsigned short f2b(float x) {
    return __bfloat16_as_ushort(__float2bfloat16(x));
}
__device__ inline float b2f(unsigned short u) {
    return __uint_as_float(((unsigned)u) << 16);
}

__device__ __forceinline__ void gload_lds16(const void* g, void* l) {
    __builtin_amdgcn_global_load_lds(
        (const __attribute__((address_space(1))) void*)g,
        (__attribute__((address_space(3))) void*)l, 16, 0, 0);
}

// ===================== cooperative CSR construction ========================
// One launch, phases separated by grid.sync(). Grid must be exactly
// NB = ceil(n/256) blocks (one 256-chunk per block for the scan phases);
// hist/fill grid-stride over E.

__launch_bounds__(256, 4)
__global__ void csr_build(const int* __restrict__ src, const int* __restrict__ dst,
                          int* __restrict__ degi, int* __restrict__ bsum,
                          int* __restrict__ rowptr, int* __restrict__ cursor,
                          int* __restrict__ csr, int n, int E, int nb) {
    cg::grid_group grid = cg::this_grid();
    __shared__ int s[256];
    __shared__ int carry;

    const int tid = threadIdx.x;
    const int gtid = (int)blockIdx.x * 256 + tid;
    const int gsz = (int)gridDim.x * 256;

    // P0: zero degree histogram
    for (int i = gtid; i < n; i += gsz) degi[i] = 0;
    grid.sync();

    // P1: histogram of dst
    for (int e = gtid; e < E; e += gsz) atomicAdd(&degi[dst[e]], 1);
    grid.sync();

    // P2: per-block (256-chunk) reduction -> bsum[b]
    {
        int v = (gtid < n) ? degi[gtid] : 0;
        s[tid] = v;
        __syncthreads();
        for (int off = 128; off > 0; off >>= 1) {
            if (tid < off) s[tid] += s[tid + off];
            __syncthreads();
        }
        if (tid == 0) bsum[blockIdx.x] = s[0];
    }
    grid.sync();

    // P3: block 0 exclusive-scans bsum[0..nb) in 256-tiles with carry
    if (blockIdx.x == 0) {
        if (tid == 0) carry = 0;
        __syncthreads();
        for (int base = 0; base < nb; base += 256) {
            const int idx = base + tid;
            const int val = (idx < nb) ? bsum[idx] : 0;
            s[tid] = val;
            __syncthreads();
            for (int off = 1; off < 256; off <<= 1) {
                int add = (tid >= off) ? s[tid - off] : 0;
                __syncthreads();
                s[tid] += add;
                __syncthreads();
            }
            const int incl = s[tid] + carry;          // reads old carry
            if (idx < nb) bsum[idx] = incl - val;     // exclusive
            __syncthreads();                          // all incl computed
            if (tid == 255) carry = incl;             // new carry = tile total
            __syncthreads();
        }
    }
    grid.sync();

    // P4: per-block inclusive scan of chunk + bsum offset -> rowptr, cursor
    {
        int v = (gtid < n) ? degi[gtid] : 0;
        s[tid] = v;
        __syncthreads();
        for (int off = 1; off < 256; off <<= 1) {
            int add = (tid >= off) ? s[tid - off] : 0;
            __syncthreads();
            s[tid] += add;
            __syncthreads();
        }
        const int excl = s[tid] - v + bsum[blockIdx.x];
        if (gtid < n) {
            rowptr[gtid] = excl;
            cursor[gtid] = excl;
        }
        if (gtid == 0) rowptr[n] = E;
    }
    grid.sync();

    // P5: fill CSR adjacency
    for (int e = gtid; e < E; e += gsz) {
        int pos = atomicAdd(&cursor[dst[e]], 1);
        csr[pos] = src[e];
    }
}

// ====================== layer-1 MFMA projection (LDS x) ====================
// 128 -> (64|64). fp32 input. Proven R11/R12 structure: CH=2 block col-split
// (XCD-paired), 16 KB fragment-order weights, 64-row fp32 x tiles dbuf'd via
// global_load_lds with XOR swizzle c^(r&7) (source + read).
// MFMA 16x16x32: A[m=lane&15][k=(lane>>4)*8+i]; D col=lane&15,
// row=(lane>>4)*4+reg (verified R3-R6).

__launch_bounds__(256, 2)
__global__ void proj1_mfma(const float* __restrict__ x,
                           const float* __restrict__ Wl,
                           const float* __restrict__ Wr,
                           const float* __restrict__ bl,
                           unsigned short* __restrict__ pv,
                           unsigned short* __restrict__ rv,
                           int n) {
    constexpr int S = 4;             // k-steps (128/32)
    constexpr int TWB = 4;           // weight col-tiles staged per block
    constexpr int NCH = TWB * S * 64;

    __shared__ __attribute__((aligned(16))) unsigned short sW[NCH * 8];   // 16 KB
    __shared__ __attribute__((aligned(16))) float sX[2][64 * 128];        // 2 x 32 KB

    const int b = (int)blockIdx.x;
    const int ch = (b >> 3) & 1;
    const int blk = (b & 7) | ((b >> 4) << 3);
    const int nblk = (int)gridDim.x >> 1;

    const int tid = threadIdx.x;
    // stage this block's ch-half of weights as lane-ordered fragments
    for (int chunk = tid; chunk < NCH; chunk += 256) {
        const int lane_c = chunk & 63;
        const int rest = chunk >> 6;         // t*S + s
        const int s = rest % S;
        const int t = rest / S;
        const int c = (ch * TWB + t) * 16 + (lane_c & 15);
        const int k0 = s * 32 + (lane_c >> 4) * 8;
        short8 pack;
#pragma unroll
        for (int j = 0; j < 8; ++j) {
            const int k = k0 + j;
            float w = (c < 64) ? Wl[k * 64 + c] : Wr[k * 64 + (c - 64)];
            pack[j] = (short)f2b(w);
        }
        *reinterpret_cast<short8*>(&sW[(size_t)chunk * 8]) = pack;
    }

    const int wave = tid >> 6, lane = tid & 63;
    const int rg = wave;                     // row-group 0..3
    const int q = lane >> 4, ln = lane & 15;

    int colg[4];
    float bias[4];
#pragma unroll
    for (int t = 0; t < 4; ++t) {
        colg[t] = ch * 64 + t * 16 + ln;
        bias[t] = (colg[t] >= 64) ? bl[colg[t] - 64] : 0.0f;
    }

    // async-stage one 64-row x tile into sX[d] (2048 x 16B chunks).
    // LDS slot ci holds global chunk (row = ci>>5, col = (ci&31) ^ (row&7)).
    auto stage = [&](int d, int nb) {
#pragma unroll
        for (int i = 0; i < 8; ++i) {
            const int cbase = wave * 512 + i * 64;       // wave-uniform
            const int ci = cbase + lane;
            const int rl = ci >> 5;                      // local row 0..63
            const int cc = ci & 31;                      // swizzled slot col
            int row = nb + rl;
            if (row >= n) row = n - 1;                   // clamp (stores guarded)
            const float* g = x + (size_t)row * 128 + (size_t)((cc ^ (rl & 7)) << 2);
            char* l = (char*)&sX[d][0] + (size_t)cbase * 16;
            gload_lds16(g, l);
        }
    };

    auto compute = [&](int d, int nb) {
        const int rowb = nb + rg * 16;
        const int rl = rg * 16 + ln;                     // local row
        const int swz = rl & 7;
        const float* xbase = &sX[d][(size_t)rl * 128];
        f32x4 acc[4];
#pragma unroll
        for (int t = 0; t < 4; ++t) acc[t] = (f32x4){0.f, 0.f, 0.f, 0.f};
#pragma unroll
        for (int s = 0; s < S; ++s) {
            const int c0 = s * 8 + q * 2;                // 16B chunk col
            float4 v0 = *reinterpret_cast<const float4*>(xbase + ((c0 ^ swz) << 2));
            float4 v1 = *reinterpret_cast<const float4*>(xbase + (((c0 + 1) ^ swz) << 2));
            short8 a;
            a[0] = (short)f2b(v0.x); a[1] = (short)f2b(v0.y);
            a[2] = (short)f2b(v0.z); a[3] = (short)f2b(v0.w);
            a[4] = (short)f2b(v1.x); a[5] = (short)f2b(v1.y);
            a[6] = (short)f2b(v1.z); a[7] = (short)f2b(v1.w);
#pragma unroll
            for (int t = 0; t < 4; ++t) {
                short8 bf = *reinterpret_cast<const short8*>(
                    &sW[((size_t)(t * S + s)) * 512 + (size_t)lane * 8]);
                acc[t] = __builtin_amdgcn_mfma_f32_16x16x32_bf16(a, bf, acc[t], 0, 0, 0);
            }
        }
#pragma unroll
        for (int t = 0; t < 4; ++t) {
            const int c = colg[t];
#pragma unroll
            for (int rr = 0; rr < 4; ++rr) {
                const int row = rowb + q * 4 + rr;
                if (row < n) {
                    if (c < 64)
                        pv[(size_t)row * 64 + c] = f2b(acc[t][rr]);
                    else
                        rv[(size_t)row * 64 + (c - 64)] = f2b(acc[t][rr] + bias[t]);
                }
            }
        }
    };

    constexpr int npi = 64;
    const int stride = nblk * npi;
    int nb = blk * npi;
    if (nb >= n) return;
    stage(0, nb);
    __syncthreads();          // weights + tile0 ready
    while (true) {
        const int nb1 = nb + stride;
        if (nb1 < n) stage(1, nb1);
        compute(0, nb);
        __syncthreads();      // tile1 arrived; sX[0] free
        if (nb1 >= n) break;
        const int nb2 = nb1 + stride;
        if (nb2 < n) stage(0, nb2);
        compute(1, nb1);
        __syncthreads();
        nb = nb2;
        if (nb >= n) break;
    }
}

// ================= layers 2/3 MFMA projection (LDS-DMA, bf16 in) ==========
// Same structure as proj1 but bf16 input rows (no cvt: A-frag is a direct
// swizzled ds_read_b128) and CH=1 (weights tiny). CR = DIN/8 16B chunks per
// row; swizzle mask CR-1. 64-row tiles, double-buffered.

template <int DIN, int DP, int DR, int DT2, bool RELU, bool OUT_BF16>
__launch_bounds__(256, 4)
__global__ void proj_lds(const unsigned short* __restrict__ xv,
                         const float* __restrict__ Wl,
                         const float* __restrict__ Wr,
                         const float* __restrict__ bl,
                         void* __restrict__ pv,
                         void* __restrict__ rv,
                         int n) {
    constexpr int S = DIN / 32;              // MFMA k-steps
    constexpr int TILES = DT2 / 16;          // col tiles (all owned per block)
    constexpr int CR = DIN / 8;              // 16B chunks per bf16 row
    constexpr int NCH = TILES * S * 64;      // weight fragment chunks

    __shared__ __attribute__((aligned(16))) unsigned short sW[NCH * 8];
    __shared__ __attribute__((aligned(16))) unsigned short sX[2][64 * DIN];

    const int blk = (int)blockIdx.x;
    const int nblk = (int)gridDim.x;
    const int tid = threadIdx.x;

    // stage weights as lane-ordered fragments (proven R6 layout)
    for (int chunk = tid; chunk < NCH; chunk += 256) {
        const int lane_c = chunk & 63;
        const int rest = chunk >> 6;         // t*S + s
        const int s = rest % S;
        const int t = rest / S;
        const int c = t * 16 + (lane_c & 15);
        const int k0 = s * 32 + (lane_c >> 4) * 8;
        short8 pack;
#pragma unroll
        for (int j = 0; j < 8; ++j) {
            float w = 0.f;
            const int k = k0 + j;
            if (c < DP) w = Wl[k * DP + c];
            else if (c < DP + DR) w = Wr[k * DR + (c - DP)];
            pack[j] = (short)f2b(w);
        }
        *reinterpret_cast<short8*>(&sW[(size_t)chunk * 8]) = pack;
    }

    const int wave = tid >> 6, lane = tid & 63;
    const int rg = wave;                     // row-group 0..3
    const int q = lane >> 4, ln = lane & 15;

    int colg[TILES];
    float bias[TILES];
#pragma unroll
    for (int t = 0; t < TILES; ++t) {
        colg[t] = t * 16 + ln;
        bias[t] = (colg[t] >= DP && colg[t] < DP + DR) ? bl[colg[t] - DP] : 0.0f;
    }

    // async-stage one 64-row bf16 tile (64*CR chunks); slot ci holds global
    // chunk (row = ci/CR, col = (ci%CR) ^ (row & (CR-1))).
    auto stage = [&](int d, int nb) {
#pragma unroll
        for (int i = 0; i < CR / 4; ++i) {
            const int cbase = wave * (16 * CR) + i * 64; // wave-uniform
            const int ci = cbase + lane;
            const int rl = ci / CR;                      // local row 0..63
            const int cc = ci & (CR - 1);                // swizzled slot col
            int row = nb + rl;
            if (row >= n) row = n - 1;                   // clamp (stores guarded)
            const unsigned short* g =
                xv + (size_t)row * DIN + (size_t)((cc ^ (rl & (CR - 1))) << 3);
            char* l = (char*)&sX[d][0] + (size_t)cbase * 16;
            gload_lds16(g, l);
        }
    };

    auto compute = [&](int d, int nb) {
        const int rl = rg * 16 + ln;                     // local row
        const int swz = rl & (CR - 1);
        const unsigned short* rowb = &sX[d][(size_t)rl * DIN];
        f32x4 acc[TILES];
#pragma unroll
        for (int t = 0; t < TILES; ++t) acc[t] = (f32x4){0.f, 0.f, 0.f, 0.f};
#pragma unroll
        for (int s = 0; s < S; ++s) {
            const int c0 = s * 4 + q;                    // 16B chunk col
            short8 a = *reinterpret_cast<const short8*>(rowb + (size_t)((c0 ^ swz) << 3));
            if (RELU) {
#pragma unroll
                for (int j = 0; j < 8; ++j)
                    a[j] = ((short)a[j] < 0) ? (short)0 : a[j];
            }
#pragma unroll
            for (int t = 0; t < TILES; ++t) {
                short8 bf = *reinterpret_cast<const short8*>(
                    &sW[((size_t)(t * S + s)) * 512 + (size_t)lane * 8]);
                acc[t] = __builtin_amdgcn_mfma_f32_16x16x32_bf16(a, bf, acc[t], 0, 0, 0);
            }
        }
        const int rowbase = nb + rg * 16 + q * 4;
#pragma unroll
        for (int t = 0; t < TILES; ++t) {
            const int c = colg[t];
#pragma unroll
            for (int rr = 0; rr < 4; ++rr) {
                const int row = rowbase + rr;
                if (row < n) {
                    if (c < DP) {
                        if constexpr (OUT_BF16)
                            ((unsigned short*)pv)[(size_t)row * DP + c] = f2b(acc[t][rr]);
                        else
                            ((float*)pv)[(size_t)row * DP + c] = acc[t][rr];
                    } else if (c < DP + DR) {
                        const float v = acc[t][rr] + bias[t];
                        if constexpr (OUT_BF16)
                            ((unsigned short*)rv)[(size_t)row * DR + (c - DP)] = f2b(v);
                        else
                            ((float*)rv)[(size_t)row * DR + (c - DP)] = v;
                    }
                }
            }
        }
    };

    constexpr int npi = 64;
    const int stride = nblk * npi;
    int nb = blk * npi;
    if (nb >= n) return;
    stage(0, nb);
    __syncthreads();          // weights + tile0 ready
    while (true) {
        const int nb1 = nb + stride;
        if (nb1 < n) stage(1, nb1);
        compute(0, nb);
        __syncthreads();      // tile1 arrived; sX[0] free
        if (nb1 >= n) break;
        const int nb2 = nb1 + stride;
        if (nb2 < n) stage(0, nb2);
        compute(1, nb1);
        __syncthreads();
        nb = nb2;
        if (nb >= n) break;
    }
}

// ============================ aggregation ==================================
// out[d] += mean over csr row of p rows. bf16 buffers: L=D/8 lanes per node,
// one short8 per lane per gathered row; fp32 accumulation; unroll-4 keeps
// 4 independent csr->row chains in flight.

template <int D, int L>
__global__ void agg_bf16(const int* __restrict__ rowptr,
                         const int* __restrict__ csr,
                         const unsigned short* __restrict__ p,
                         unsigned short* __restrict__ out,
                         int n) {
    constexpr int RQ = D / 8;            // short8s per row
    long long gid = (long long)blockIdx.x * blockDim.x + threadIdx.x;
    int d = (int)(gid / L);
    int l = (int)(gid % L);
    if (d >= n) return;
    int beg = rowptr[d], end = rowptr[d + 1];
    int deg = end - beg;
    if (deg <= 0) return;

    const short8* pr = reinterpret_cast<const short8*>(p);
    float s[8];
#pragma unroll
    for (int j = 0; j < 8; ++j) s[j] = 0.0f;

    int i = beg;
    for (; i + 4 <= end; i += 4) {
        int e0 = csr[i], e1 = csr[i + 1], e2 = csr[i + 2], e3 = csr[i + 3];
        short8 a = pr[(size_t)e0 * RQ + l];
        short8 b = pr[(size_t)e1 * RQ + l];
        short8 c = pr[(size_t)e2 * RQ + l];
        short8 e = pr[(size_t)e3 * RQ + l];
#pragma unroll
        for (int j = 0; j < 8; ++j)
            s[j] += (b2f((unsigned short)a[j]) + b2f((unsigned short)b[j])) +
                    (b2f((unsigned short)c[j]) + b2f((unsigned short)e[j]));
    }
    for (; i < end; ++i) {
        short8 a = pr[(size_t)csr[i] * RQ + l];
#pragma unroll
        for (int j = 0; j < 8; ++j) s[j] += b2f((unsigned short)a[j]);
    }

    const float inv = 1.0f / (float)deg;
    short8* o = reinterpret_cast<short8*>(out) + (size_t)d * RQ + l;
    short8 cur = *o;
#pragma unroll
    for (int j = 0; j < 8; ++j) {
        float v = b2f((unsigned short)cur[j]) + s[j] * inv;
        cur[j] = (short)f2b(v);
    }
    *o = cur;
}

// fp32 variant for the final layer (out = d_out, fp32); L lanes per node,
// one float4 per lane (L == D/4, all lanes active).
template <int D, int L>
__global__ void agg_f32(const int* __restrict__ rowptr,
                        const int* __restrict__ csr,
                        const float* __restrict__ p,
                        float* __restrict__ out,
                        int n) {
    constexpr int RQ = D / 4;            // float4s per row
    static_assert(L == RQ, "agg_f32: one float4 per lane");
    long long gid = (long long)blockIdx.x * blockDim.x + threadIdx.x;
    int d = (int)(gid / L);
    int l = (int)(gid % L);
    if (d >= n) return;
    int beg = rowptr[d], end = rowptr[d + 1];
    int deg = end - beg;
    if (deg <= 0) return;

    const float4* pr = reinterpret_cast<const float4*>(p);
    float sx = 0.f, sy = 0.f, sz = 0.f, sw = 0.f;
    int i = beg;
    for (; i + 4 <= end; i += 4) {
        int s0 = csr[i], s1 = csr[i + 1], s2 = csr[i + 2], s3 = csr[i + 3];
        float4 a = pr[(size_t)s0 * RQ + l];
        float4 b = pr[(size_t)s1 * RQ + l];
        float4 c = pr[(size_t)s2 * RQ + l];
        float4 e = pr[(size_t)s3 * RQ + l];
        sx += (a.x + b.x) + (c.x + e.x);
        sy += (a.y + b.y) + (c.y + e.y);
        sz += (a.z + b.z) + (c.z + e.z);
        sw += (a.w + b.w) + (c.w + e.w);
    }
    for (; i < end; ++i) {
        float4 a = pr[(size_t)csr[i] * RQ + l];
        sx += a.x; sy += a.y; sz += a.z; sw += a.w;
    }
    const float inv = 1.0f / (float)deg;
    float4* o = reinterpret_cast<float4*>(out) + (size_t)d * RQ + l;
    float4 cur = *o;
    cur.x += sx * inv; cur.y += sy * inv;
    cur.z += sz * inv; cur.w += sw * inv;
    *o = cur;
}

// ============================ launcher =====================================

extern "C" void kernel_launch(void* const* d_in, const int* in_sizes, int n_in,
                              void* d_out, int out_size, void* d_ws, size_t ws_size,
                              hipStream_t stream) {
    const float* x   = (const float*)d_in[0];
    const int*   ei  = (const int*)d_in[1];   // (2, E) int32
    const float* Wl1 = (const float*)d_in[2];
    const float* bl1 = (const float*)d_in[3];
    const float* Wr1 = (const float*)d_in[4];
    const float* Wl2 = (const float*)d_in[5];
    const float* bl2 = (const float*)d_in[6];
    const float* Wr2 = (const float*)d_in[7];
    const float* Wl3 = (const float*)d_in[8];
    const float* bl3 = (const float*)d_in[9];
    const float* Wr3 = (const float*)d_in[10];
    float* out = (float*)d_out;

    const int N = in_sizes[0] / 128;
    const int E = in_sizes[1] / 2;
    const int* src  = ei;
    const int* dstp = ei + E;

    // workspace (bf16 intermediates):
    //   A1 bf16 N*64 | B bf16 N*64 | A2 bf16 N*32 | C bf16 N*32 |
    //   A3 f32 N*20 | rowptr (N+1) | csr (E)
    // transient CSR ints (degi, cursor, bsum) alias A3 (dead before proj3).
    unsigned short* A1 = (unsigned short*)d_ws;
    unsigned short* Bb = A1 + (size_t)N * 64;
    unsigned short* A2 = Bb + (size_t)N * 64;
    unsigned short* Cb = A2 + (size_t)N * 32;
    float* A3 = (float*)(Cb + (size_t)N * 32);
    int* rowptr = (int*)(A3 + (size_t)N * 20);
    int* csr    = rowptr + (N + 1);

    int* degi   = (int*)A3;
    int* cursor = degi + N;
    int* bsum   = cursor + N;

    const int NB = (N + 255) / 256;  // 782

    // --- CSR build: ONE cooperative kernel (zero/hist/scan/fill fused) ---
    {
        int n_ = N, e_ = E, nb_ = NB;
        void* args[] = {(void*)&src, (void*)&dstp, (void*)&degi, (void*)&bsum,
                        (void*)&rowptr, (void*)&cursor, (void*)&csr,
                        (void*)&n_, (void*)&e_, (void*)&nb_};
        hipLaunchCooperativeKernel(reinterpret_cast<void*>(csr_build),
                                   dim3(NB), dim3(256), args, 0, stream);
    }

    // --- layer 1: 128 -> 64 --- fp32 in, bf16 out; LDS-staged x (async DMA)
    // 80 KB LDS (16 W + 64 x-dbuf swizzled), 2 blocks/CU; grid 512 =
    // 256 node-blocks x 2 ch classes, pairs (b, b^8) per XCD.
    proj1_mfma<<<512, 256, 0, stream>>>(x, Wl1, Wr1, bl1, A1, Bb, N);
    agg_bf16<64, 8><<<(int)(((long long)N * 8 + 255) / 256), 256, 0, stream>>>(
        rowptr, csr, A1, Bb, N);

    // --- layer 2: 64 -> 32 --- bf16 in (relu), bf16 out; LDS-DMA path
    proj_lds<64, 32, 32, 64, true, true><<<1024, 256, 0, stream>>>(
        Bb, Wl2, Wr2, bl2, A2, Cb, N);
    agg_bf16<32, 4><<<(int)(((long long)N * 4 + 255) / 256), 256, 0, stream>>>(
        rowptr, csr, A2, Cb, N);

    // --- layer 3: 32 -> 20 --- bf16 in (relu), fp32 out (p3=A3, r -> d_out)
    proj_lds<32, 20, 20, 48, true, false><<<1024, 256, 0, stream>>>(
        Cb, Wl3, Wr3, bl3, A3, out, N);
    agg_f32<20, 5><<<(int)(((long long)N * 5 + 255) / 256), 256, 0, stream>>>(
        rowptr, csr, A3, out, N);
}

// Round 9
// 334.294 us; speedup vs baseline: 2.2038x; 2.2038x over previous
//
#include <hip/hip_runtime.h>
#include <hip/hip_bf16.h>

// ---------------------------------------------------------------------------
// GraphSAGE 3-layer encoder, fp32 in/out.
//   per layer: h_out = relu?( mean_agg(h)@Wl + b + h@Wr )
// Identity: segment_sum(h[src])@Wl == segment_sum((h@Wl)[src])
//   -> project first (MFMA bf16), aggregate small vectors via CSR gather.
// R15 (fixed compile) :
//   * R14 post-mortem: cooperative grid.sync() costs ~90 us/sync at 782
//     blocks -> csr_build 473 us. REVERTED. But it quantified the old
//     6-kernel CSR chain at ~70 us (bigger than proj1!).
//   * R15: compress the chain WITHOUT grid sync:
//     - CSR segments need not be node-ordered: aggs read (rowptr[d], deg[d])
//       instead of rowptr[d+1]. Segment bases allocated per 256-node block
//       by ONE atomicAdd on a global counter -> the 3-kernel scan (incl.
//       the serial single-block scan_top) becomes ONE scan_alloc kernel.
//     - hist is input-independent of proj1 -> fused into proj1 (grid-stride
//       fire-and-forget atomics before weight staging; 2.5 MB rides free
//       under proj1's 100 MB).
//     - chain: memset(deg+counter) -> [proj1|hist] -> scan_alloc -> fill.
//   * deg becomes persistent (after csr); cursor aliases A3 (transient).
//   * R16 fix: removed the forward-referenced sF_cast helper (compile error);
//     direct indexing restored.
// ---------------------------------------------------------------------------

typedef __attribute__((ext_vector_type(8))) short short8;
typedef __attribute__((ext_vector_type(4))) float f32x4;

__device__ inline unsigned short f2b(float x) {
    return __bfloat16_as_ushort(__float2bfloat16(x));
}
__device__ inline float b2f(unsigned short u) {
    return __uint_as_float(((unsigned)u) << 16);
}

__device__ __forceinline__ void gload_lds16(const void* g, void* l) {
    __builtin_amdgcn_global_load_lds(
        (const __attribute__((address_space(1))) void*)g,
        (__attribute__((address_space(3))) void*)l, 16, 0, 0);
}

// ============================ CSR construction =============================
// scan_alloc: per-256-node block: LDS inclusive scan of degrees, one
// atomicAdd(counter, blockTotal) for the base, write rowptr/cursor.
// Segment order across blocks is arbitrary (allowed: aggs use deg[]).

__global__ void scan_alloc(const int* __restrict__ deg, int* __restrict__ counter,
                           int* __restrict__ rowptr, int* __restrict__ cursor,
                           int n) {
    __shared__ int s[256];
    __shared__ int base;
    const int tid = threadIdx.x;
    const int i = (int)blockIdx.x * 256 + tid;
    const int v = (i < n) ? deg[i] : 0;
    s[tid] = v;
    __syncthreads();
    for (int off = 1; off < 256; off <<= 1) {
        int add = (tid >= off) ? s[tid - off] : 0;
        __syncthreads();
        s[tid] += add;
        __syncthreads();
    }
    if (tid == 255) base = atomicAdd(counter, s[255]);
    __syncthreads();
    const int excl = s[tid] - v + base;
    if (i < n) {
        rowptr[i] = excl;
        cursor[i] = excl;
    }
}

__global__ void fill_kernel(const int* __restrict__ src, const int* __restrict__ dst,
                            int* __restrict__ cursor, int* __restrict__ csr, int E) {
    int e = blockIdx.x * blockDim.x + threadIdx.x;
    if (e < E) {
        int pos = atomicAdd(&cursor[dst[e]], 1);
        csr[pos] = src[e];
    }
}

// ====================== layer-1 MFMA projection (LDS x) ====================
// 128 -> (64|64). fp32 input. Proven R11/R12 structure: CH=2 block col-split
// (XCD-paired), 16 KB fragment-order weights, 64-row fp32 x tiles dbuf'd via
// global_load_lds with XOR swizzle c^(r&7) (source + read).
// R15: degree histogram fused in (grid-stride fire-and-forget atomics,
// issued before weight staging; completes within this dispatch).
// MFMA 16x16x32: A[m=lane&15][k=(lane>>4)*8+i]; D col=lane&15,
// row=(lane>>4)*4+reg (verified R3-R6).

__launch_bounds__(256, 2)
__global__ void proj1_mfma(const float* __restrict__ x,
                           const float* __restrict__ Wl,
                           const float* __restrict__ Wr,
                           const float* __restrict__ bl,
                           unsigned short* __restrict__ pv,
                           unsigned short* __restrict__ rv,
                           const int* __restrict__ dst,
                           int* __restrict__ deg,
                           int n, int E) {
    constexpr int S = 4;             // k-steps (128/32)
    constexpr int TWB = 4;           // weight col-tiles staged per block
    constexpr int NCH = TWB * S * 64;

    __shared__ __attribute__((aligned(16))) unsigned short sW[NCH * 8];   // 16 KB
    __shared__ __attribute__((aligned(16))) float sX[2][64 * 128];        // 2 x 32 KB

    const int b = (int)blockIdx.x;
    const int ch = (b >> 3) & 1;
    const int blk = (b & 7) | ((b >> 4) << 3);
    const int nblk = (int)gridDim.x >> 1;

    const int tid = threadIdx.x;

    // fused degree histogram (independent of projection inputs)
    {
        const int gsz = (int)gridDim.x * 256;
        for (int e = b * 256 + tid; e < E; e += gsz)
            atomicAdd(&deg[dst[e]], 1);
    }

    // stage this block's ch-half of weights as lane-ordered fragments
    for (int chunk = tid; chunk < NCH; chunk += 256) {
        const int lane_c = chunk & 63;
        const int rest = chunk >> 6;         // t*S + s
        const int s = rest % S;
        const int t = rest / S;
        const int c = (ch * TWB + t) * 16 + (lane_c & 15);
        const int k0 = s * 32 + (lane_c >> 4) * 8;
        short8 pack;
#pragma unroll
        for (int j = 0; j < 8; ++j) {
            const int k = k0 + j;
            float w = (c < 64) ? Wl[k * 64 + c] : Wr[k * 64 + (c - 64)];
            pack[j] = (short)f2b(w);
        }
        *reinterpret_cast<short8*>(&sW[(size_t)chunk * 8]) = pack;
    }

    const int wave = tid >> 6, lane = tid & 63;
    const int rg = wave;                     // row-group 0..3
    const int q = lane >> 4, ln = lane & 15;

    int colg[4];
    float bias[4];
#pragma unroll
    for (int t = 0; t < 4; ++t) {
        colg[t] = ch * 64 + t * 16 + ln;
        bias[t] = (colg[t] >= 64) ? bl[colg[t] - 64] : 0.0f;
    }

    // async-stage one 64-row x tile into sX[d] (2048 x 16B chunks).
    // LDS slot ci holds global chunk (row = ci>>5, col = (ci&31) ^ (row&7)).
    auto stage = [&](int d, int nb) {
#pragma unroll
        for (int i = 0; i < 8; ++i) {
            const int cbase = wave * 512 + i * 64;       // wave-uniform
            const int ci = cbase + lane;
            const int rl = ci >> 5;                      // local row 0..63
            const int cc = ci & 31;                      // swizzled slot col
            int row = nb + rl;
            if (row >= n) row = n - 1;                   // clamp (stores guarded)
            const float* g = x + (size_t)row * 128 + (size_t)((cc ^ (rl & 7)) << 2);
            char* l = (char*)&sX[d][0] + (size_t)cbase * 16;
            gload_lds16(g, l);
        }
    };

    auto compute = [&](int d, int nb) {
        const int rowb = nb + rg * 16;
        const int rl = rg * 16 + ln;                     // local row
        const int swz = rl & 7;
        const float* xbase = &sX[d][(size_t)rl * 128];
        f32x4 acc[4];
#pragma unroll
        for (int t = 0; t < 4; ++t) acc[t] = (f32x4){0.f, 0.f, 0.f, 0.f};
#pragma unroll
        for (int s = 0; s < S; ++s) {
            const int c0 = s * 8 + q * 2;                // 16B chunk col
            float4 v0 = *reinterpret_cast<const float4*>(xbase + ((c0 ^ swz) << 2));
            float4 v1 = *reinterpret_cast<const float4*>(xbase + (((c0 + 1) ^ swz) << 2));
            short8 a;
            a[0] = (short)f2b(v0.x); a[1] = (short)f2b(v0.y);
            a[2] = (short)f2b(v0.z); a[3] = (short)f2b(v0.w);
            a[4] = (short)f2b(v1.x); a[5] = (short)f2b(v1.y);
            a[6] = (short)f2b(v1.z); a[7] = (short)f2b(v1.w);
#pragma unroll
            for (int t = 0; t < 4; ++t) {
                short8 bf = *reinterpret_cast<const short8*>(
                    &sW[((size_t)(t * S + s)) * 512 + (size_t)lane * 8]);
                acc[t] = __builtin_amdgcn_mfma_f32_16x16x32_bf16(a, bf, acc[t], 0, 0, 0);
            }
        }
#pragma unroll
        for (int t = 0; t < 4; ++t) {
            const int c = colg[t];
#pragma unroll
            for (int rr = 0; rr < 4; ++rr) {
                const int row = rowb + q * 4 + rr;
                if (row < n) {
                    if (c < 64)
                        pv[(size_t)row * 64 + c] = f2b(acc[t][rr]);
                    else
                        rv[(size_t)row * 64 + (c - 64)] = f2b(acc[t][rr] + bias[t]);
                }
            }
        }
    };

    constexpr int npi = 64;
    const int stride = nblk * npi;
    int nb = blk * npi;
    if (nb >= n) return;
    stage(0, nb);
    __syncthreads();          // weights + tile0 ready
    while (true) {
        const int nb1 = nb + stride;
        if (nb1 < n) stage(1, nb1);
        compute(0, nb);
        __syncthreads();      // tile1 arrived; sX[0] free
        if (nb1 >= n) break;
        const int nb2 = nb1 + stride;
        if (nb2 < n) stage(0, nb2);
        compute(1, nb1);
        __syncthreads();
        nb = nb2;
        if (nb >= n) break;
    }
}

// ================= layers 2/3 MFMA projection (LDS-DMA, bf16 in) ==========
// Same structure as proj1 but bf16 input rows (no cvt: A-frag is a direct
// swizzled ds_read_b128) and CH=1 (weights tiny). CR = DIN/8 16B chunks per
// row; swizzle mask CR-1. 64-row tiles, double-buffered.

template <int DIN, int DP, int DR, int DT2, bool RELU, bool OUT_BF16>
__launch_bounds__(256, 4)
__global__ void proj_lds(const unsigned short* __restrict__ xv,
                         const float* __restrict__ Wl,
                         const float* __restrict__ Wr,
                         const float* __restrict__ bl,
                         void* __restrict__ pv,
                         void* __restrict__ rv,
                         int n) {
    constexpr int S = DIN / 32;              // MFMA k-steps
    constexpr int TILES = DT2 / 16;          // col tiles (all owned per block)
    constexpr int CR = DIN / 8;              // 16B chunks per bf16 row
    constexpr int NCH = TILES * S * 64;      // weight fragment chunks

    __shared__ __attribute__((aligned(16))) unsigned short sW[NCH * 8];
    __shared__ __attribute__((aligned(16))) unsigned short sX[2][64 * DIN];

    const int blk = (int)blockIdx.x;
    const int nblk = (int)gridDim.x;
    const int tid = threadIdx.x;

    // stage weights as lane-ordered fragments (proven R6 layout)
    for (int chunk = tid; chunk < NCH; chunk += 256) {
        const int lane_c = chunk & 63;
        const int rest = chunk >> 6;         // t*S + s
        const int s = rest % S;
        const int t = rest / S;
        const int c = t * 16 + (lane_c & 15);
        const int k0 = s * 32 + (lane_c >> 4) * 8;
        short8 pack;
#pragma unroll
        for (int j = 0; j < 8; ++j) {
            float w = 0.f;
            const int k = k0 + j;
            if (c < DP) w = Wl[k * DP + c];
            else if (c < DP + DR) w = Wr[k * DR + (c - DP)];
            pack[j] = (short)f2b(w);
        }
        *reinterpret_cast<short8*>(&sW[(size_t)chunk * 8]) = pack;
    }
    __syncthreads();

    const int wave = tid >> 6, lane = tid & 63;
    const int rg = wave;                     // row-group 0..3
    const int q = lane >> 4, ln = lane & 15;

    int colg[TILES];
    float bias[TILES];
#pragma unroll
    for (int t = 0; t < TILES; ++t) {
        colg[t] = t * 16 + ln;
        bias[t] = (colg[t] >= DP && colg[t] < DP + DR) ? bl[colg[t] - DP] : 0.0f;
    }

    // async-stage one 64-row bf16 tile (64*CR chunks); slot ci holds global
    // chunk (row = ci/CR, col = (ci%CR) ^ (row & (CR-1))).
    auto stage = [&](int d, int nb) {
#pragma unroll
        for (int i = 0; i < CR / 4; ++i) {
            const int cbase = wave * (16 * CR) + i * 64; // wave-uniform
            const int ci = cbase + lane;
            const int rl = ci / CR;                      // local row 0..63
            const int cc = ci & (CR - 1);                // swizzled slot col
            int row = nb + rl;
            if (row >= n) row = n - 1;                   // clamp (stores guarded)
            const unsigned short* g =
                xv + (size_t)row * DIN + (size_t)((cc ^ (rl & (CR - 1))) << 3);
            char* l = (char*)&sX[d][0] + (size_t)cbase * 16;
            gload_lds16(g, l);
        }
    };

    auto compute = [&](int d, int nb) {
        const int rl = rg * 16 + ln;                     // local row
        const int swz = rl & (CR - 1);
        const unsigned short* rowb = &sX[d][(size_t)rl * DIN];
        f32x4 acc[TILES];
#pragma unroll
        for (int t = 0; t < TILES; ++t) acc[t] = (f32x4){0.f, 0.f, 0.f, 0.f};
#pragma unroll
        for (int s = 0; s < S; ++s) {
            const int c0 = s * 4 + q;                    // 16B chunk col
            short8 a = *reinterpret_cast<const short8*>(rowb + (size_t)((c0 ^ swz) << 3));
            if (RELU) {
#pragma unroll
                for (int j = 0; j < 8; ++j)
                    a[j] = ((short)a[j] < 0) ? (short)0 : a[j];
            }
#pragma unroll
            for (int t = 0; t < TILES; ++t) {
                short8 bf = *reinterpret_cast<const short8*>(
                    &sW[((size_t)(t * S + s)) * 512 + (size_t)lane * 8]);
                acc[t] = __builtin_amdgcn_mfma_f32_16x16x32_bf16(a, bf, acc[t], 0, 0, 0);
            }
        }
        const int rowbase = nb + rg * 16 + q * 4;
#pragma unroll
        for (int t = 0; t < TILES; ++t) {
            const int c = colg[t];
#pragma unroll
            for (int rr = 0; rr < 4; ++rr) {
                const int row = rowbase + rr;
                if (row < n) {
                    if (c < DP) {
                        if constexpr (OUT_BF16)
                            ((unsigned short*)pv)[(size_t)row * DP + c] = f2b(acc[t][rr]);
                        else
                            ((float*)pv)[(size_t)row * DP + c] = acc[t][rr];
                    } else if (c < DP + DR) {
                        const float v = acc[t][rr] + bias[t];
                        if constexpr (OUT_BF16)
                            ((unsigned short*)rv)[(size_t)row * DR + (c - DP)] = f2b(v);
                        else
                            ((float*)rv)[(size_t)row * DR + (c - DP)] = v;
                    }
                }
            }
        }
    };

    constexpr int npi = 64;
    const int stride = nblk * npi;
    int nb = blk * npi;
    if (nb >= n) return;
    stage(0, nb);
    __syncthreads();          // weights + tile0 ready
    while (true) {
        const int nb1 = nb + stride;
        if (nb1 < n) stage(1, nb1);
        compute(0, nb);
        __syncthreads();      // tile1 arrived; sX[0] free
        if (nb1 >= n) break;
        const int nb2 = nb1 + stride;
        if (nb2 < n) stage(0, nb2);
        compute(1, nb1);
        __syncthreads();
        nb = nb2;
        if (nb >= n) break;
    }
}

// ============================ aggregation ==================================
// out[d] += mean over csr segment of p rows. Segment = (rowptr[d], deg[d])
// (bases are block-allocated, NOT node-ordered -> rowptr[d+1] is invalid).

template <int D, int L>
__global__ void agg_bf16(const int* __restrict__ rowptr,
                         const int* __restrict__ degp,
                         const int* __restrict__ csr,
                         const unsigned short* __restrict__ p,
                         unsigned short* __restrict__ out,
                         int n) {
    constexpr int RQ = D / 8;            // short8s per row
    long long gid = (long long)blockIdx.x * blockDim.x + threadIdx.x;
    int d = (int)(gid / L);
    int l = (int)(gid % L);
    if (d >= n) return;
    int deg = degp[d];
    if (deg <= 0) return;
    int beg = rowptr[d], end = beg + deg;

    const short8* pr = reinterpret_cast<const short8*>(p);
    float s[8];
#pragma unroll
    for (int j = 0; j < 8; ++j) s[j] = 0.0f;

    int i = beg;
    for (; i + 4 <= end; i += 4) {
        int e0 = csr[i], e1 = csr[i + 1], e2 = csr[i + 2], e3 = csr[i + 3];
        short8 a = pr[(size_t)e0 * RQ + l];
        short8 b = pr[(size_t)e1 * RQ + l];
        short8 c = pr[(size_t)e2 * RQ + l];
        short8 e = pr[(size_t)e3 * RQ + l];
#pragma unroll
        for (int j = 0; j < 8; ++j)
            s[j] += (b2f((unsigned short)a[j]) + b2f((unsigned short)b[j])) +
                    (b2f((unsigned short)c[j]) + b2f((unsigned short)e[j]));
    }
    for (; i < end; ++i) {
        short8 a = pr[(size_t)csr[i] * RQ + l];
#pragma unroll
        for (int j = 0; j < 8; ++j) s[j] += b2f((unsigned short)a[j]);
    }

    const float inv = 1.0f / (float)deg;
    short8* o = reinterpret_cast<short8*>(out) + (size_t)d * RQ + l;
    short8 cur = *o;
#pragma unroll
    for (int j = 0; j < 8; ++j) {
        float v = b2f((unsigned short)cur[j]) + s[j] * inv;
        cur[j] = (short)f2b(v);
    }
    *o = cur;
}

// fp32 variant for the final layer (out = d_out, fp32); L == D/4 lanes/node.
template <int D, int L>
__global__ void agg_f32(const int* __restrict__ rowptr,
                        const int* __restrict__ degp,
                        const int* __restrict__ csr,
                        const float* __restrict__ p,
                        float* __restrict__ out,
                        int n) {
    constexpr int RQ = D / 4;            // float4s per row
    static_assert(L == RQ, "agg_f32: one float4 per lane");
    long long gid = (long long)blockIdx.x * blockDim.x + threadIdx.x;
    int d = (int)(gid / L);
    int l = (int)(gid % L);
    if (d >= n) return;
    int deg = degp[d];
    if (deg <= 0) return;
    int beg = rowptr[d], end = beg + deg;

    const float4* pr = reinterpret_cast<const float4*>(p);
    float sx = 0.f, sy = 0.f, sz = 0.f, sw = 0.f;
    int i = beg;
    for (; i + 4 <= end; i += 4) {
        int s0 = csr[i], s1 = csr[i + 1], s2 = csr[i + 2], s3 = csr[i + 3];
        float4 a = pr[(size_t)s0 * RQ + l];
        float4 b = pr[(size_t)s1 * RQ + l];
        float4 c = pr[(size_t)s2 * RQ + l];
        float4 e = pr[(size_t)s3 * RQ + l];
        sx += (a.x + b.x) + (c.x + e.x);
        sy += (a.y + b.y) + (c.y + e.y);
        sz += (a.z + b.z) + (c.z + e.z);
        sw += (a.w + b.w) + (c.w + e.w);
    }
    for (; i < end; ++i) {
        float4 a = pr[(size_t)csr[i] * RQ + l];
        sx += a.x; sy += a.y; sz += a.z; sw += a.w;
    }
    const float inv = 1.0f / (float)deg;
    float4* o = reinterpret_cast<float4*>(out) + (size_t)d * RQ + l;
    float4 cur = *o;
    cur.x += sx * inv; cur.y += sy * inv;
    cur.z += sz * inv; cur.w += sw * inv;
    *o = cur;
}

// ============================ launcher =====================================

extern "C" void kernel_launch(void* const* d_in, const int* in_sizes, int n_in,
                              void* d_out, int out_size, void* d_ws, size_t ws_size,
                              hipStream_t stream) {
    const float* x   = (const float*)d_in[0];
    const int*   ei  = (const int*)d_in[1];   // (2, E) int32
    const float* Wl1 = (const float*)d_in[2];
    const float* bl1 = (const float*)d_in[3];
    const float* Wr1 = (const float*)d_in[4];
    const float* Wl2 = (const float*)d_in[5];
    const float* bl2 = (const float*)d_in[6];
    const float* Wr2 = (const float*)d_in[7];
    const float* Wl3 = (const float*)d_in[8];
    const float* bl3 = (const float*)d_in[9];
    const float* Wr3 = (const float*)d_in[10];
    float* out = (float*)d_out;

    const int N = in_sizes[0] / 128;
    const int E = in_sizes[1] / 2;
    const int* src  = ei;
    const int* dstp = ei + E;

    // workspace:
    //   A1 bf16 N*64 | B bf16 N*64 | A2 bf16 N*32 | C bf16 N*32 |
    //   A3 f32 N*20 | rowptr (N+1) | csr (E) | deg (N) | counter (1)
    // cursor (transient, dead after fill) aliases A3.
    unsigned short* A1 = (unsigned short*)d_ws;
    unsigned short* Bb = A1 + (size_t)N * 64;
    unsigned short* A2 = Bb + (size_t)N * 64;
    unsigned short* Cb = A2 + (size_t)N * 32;
    float* A3 = (float*)(Cb + (size_t)N * 32);
    int* rowptr = (int*)(A3 + (size_t)N * 20);
    int* csr     = rowptr + (N + 1);
    int* deg     = csr + E;
    int* counter = deg + N;

    int* cursor = (int*)A3;          // transient alias

    const int NB = (N + 255) / 256;  // 782

    // --- CSR build (compressed chain) ---
    hipMemsetAsync(deg, 0, (size_t)(N + 1) * sizeof(int), stream);  // deg + counter

    // --- layer 1 (with fused degree histogram) ---
    // 80 KB LDS (16 W + 64 x-dbuf swizzled), 2 blocks/CU; grid 512 =
    // 256 node-blocks x 2 ch classes, pairs (b, b^8) per XCD.
    proj1_mfma<<<512, 256, 0, stream>>>(x, Wl1, Wr1, bl1, A1, Bb, dstp, deg, N, E);

    scan_alloc<<<NB, 256, 0, stream>>>(deg, counter, rowptr, cursor, N);
    fill_kernel<<<(E + 255) / 256, 256, 0, stream>>>(src, dstp, cursor, csr, E);

    agg_bf16<64, 8><<<(int)(((long long)N * 8 + 255) / 256), 256, 0, stream>>>(
        rowptr, deg, csr, A1, Bb, N);

    // --- layer 2: 64 -> 32 --- bf16 in (relu), bf16 out; LDS-DMA path
    proj_lds<64, 32, 32, 64, true, true><<<1024, 256, 0, stream>>>(
        Bb, Wl2, Wr2, bl2, A2, Cb, N);
    agg_bf16<32, 4><<<(int)(((long long)N * 4 + 255) / 256), 256, 0, stream>>>(
        rowptr, deg, csr, A2, Cb, N);

    // --- layer 3: 32 -> 20 --- bf16 in (relu), fp32 out (p3=A3, r -> d_out)
    proj_lds<32, 20, 20, 48, true, false><<<1024, 256, 0, stream>>>(
        Cb, Wl3, Wr3, bl3, A3, out, N);
    agg_f32<20, 5><<<(int)(((long long)N * 5 + 255) / 256), 256, 0, stream>>>(
        rowptr, deg, csr, A3, out, N);
}